// Round 15
// baseline (142.568 us; speedup 1.0000x reference)
//
#include <hip/hip_runtime.h>

// IDST (DST-III, x2) via four-step FFT (8192 = 32 x 32 x 8), real-row pairing
// (one block = 2 rows as z = x_a + j*x_b; conj symmetry recombines).
// R15 = R13 + occupancy push:
//  - transpose-1 plane: [16][256] float2 HALF-plane with ROTATION swizzle
//    col' = (col + row) & 255 (bank-clean writes AND reads; audit in text)
//    instead of 257-stride f32 padding. Plane = exactly 32768 B -> 5 blocks/CU
//    (was 33280 B -> 4). T1 now moves re+im in one b64 op (DS ops halved)
//    and the pB[32] register array is gone (-32 regs).
//  - __launch_bounds__(256,5): 5 blocks x 32 KB = exactly 160 KB LDS/CU.
//  - everything else byte-identical to R13 (no R14 hoist/ILP - those spilled).

#define NN 4096

__device__ static constexpr float TW32R[16] = {
    1.0f, 0.98078528f, 0.92387953f, 0.83146961f,
    0.70710678f, 0.55557023f, 0.38268343f, 0.19509032f,
    0.0f, -0.19509032f, -0.38268343f, -0.55557023f,
    -0.70710678f, -0.83146961f, -0.92387953f, -0.98078528f};
__device__ static constexpr float TW32I[16] = {
    0.0f, 0.19509032f, 0.38268343f, 0.55557023f,
    0.70710678f, 0.83146961f, 0.92387953f, 0.98078528f,
    1.0f, 0.98078528f, 0.92387953f, 0.83146961f,
    0.70710678f, 0.55557023f, 0.38268343f, 0.19509032f};

__device__ __forceinline__ constexpr int brev5(int x) {
    return ((x & 1) << 4) | ((x & 2) << 2) | (x & 4) | ((x & 8) >> 2) | ((x & 16) >> 4);
}

// In-register 32-point DFT, sign +1 (inverse-FFT kernel), DIF.
// Output: X[k] sits at a[brev5(k)].
__device__ __forceinline__ void fft32(float (&re)[32], float (&im)[32]) {
#pragma unroll
    for (int len = 32; len >= 2; len >>= 1) {
        const int half = len >> 1;
#pragma unroll
        for (int base = 0; base < 32; base += len) {
#pragma unroll
            for (int o = 0; o < half; ++o) {
                const int tw = o * (32 / len);
                float ur = re[base + o], ui = im[base + o];
                float vr = re[base + o + half], vi = im[base + o + half];
                re[base + o] = ur + vr;
                im[base + o] = ui + vi;
                float dr = ur - vr, di = ui - vi;
                re[base + o + half] = dr * TW32R[tw] - di * TW32I[tw];
                im[base + o + half] = dr * TW32I[tw] + di * TW32R[tw];
            }
        }
    }
}

__global__ __launch_bounds__(256, 5) void idst_fft(const float* __restrict__ x,
                                                   const float2* __restrict__ expk,
                                                   float* __restrict__ y) {
    __shared__ float2 L2[4096];          // exactly 32768 B, time-multiplexed

    const int j = threadIdx.x;
    const int blk = blockIdx.x;
    const float* xa = x + (size_t)(2 * blk) * NN;
    const float* xb = xa + NN;

    float cre[32], cim[32];

    // ---- Stage 1: b_n = a_n*(xa_n + j*xb_n)*e_n, n = 256*i + j; pad ----
#pragma unroll
    for (int i = 0; i < 16; ++i) {
        int n = j + 256 * i;
        float va = xa[n], vb = xb[n];
        if (n == NN - 1) { va *= 0.5f; vb *= 0.5f; }
        float2 e = expk[n];               // e_n = e.x + j*(-e.y)
        cre[i] = va * e.x + vb * e.y;
        cim[i] = vb * e.x - va * e.y;
    }
#pragma unroll
    for (int i = 16; i < 32; ++i) { cre[i] = 0.0f; cim[i] = 0.0f; }

    fft32(cre, cim);

    // ---- Transpose 1: two 16-row float2 half-planes, rotation swizzle ----
    const int k1 = j & 31;
    const int c2 = j >> 5;
    float dre[32], dim2[32];
    {
        float ss, sc;
        __sincosf((float)j * 7.66990393943e-4f, &ss, &sc);   // 2*pi/8192
        float tr = 1.0f, ti = 0.0f;
#pragma unroll
        for (int h = 0; h < 2; ++h) {
#pragma unroll
            for (int kk = 0; kk < 16; ++kk) {
                const int k = h * 16 + kk;
                const int s = brev5(k);
                L2[kk * 256 + ((j + k) & 255)] =
                    make_float2(cre[s] * tr - cim[s] * ti,
                                cre[s] * ti + cim[s] * tr);
                float nr = tr * sc - ti * ss;
                ti = tr * ss + ti * sc;
                tr = nr;
            }
            __syncthreads();
            if ((k1 >> 4) == h) {
#pragma unroll
                for (int c1 = 0; c1 < 32; ++c1) {
                    float2 v = L2[(k1 & 15) * 256 + ((8 * c1 + c2 + k1) & 255)];
                    dre[c1] = v.x;
                    dim2[c1] = v.y;
                }
            }
            __syncthreads();
        }
    }

    fft32(dre, dim2);

    // ---- Transpose 2 + full DFT-8 per (k1, m1), two m1-halves ----
    const float R2 = 0.70710678f;
    float sr[4][8], si[4][8];     // [p = h*2+q][m2]  (all static indexing)

    float ss2, sc2;
    __sincosf((float)c2 * 2.45436926062e-2f, &ss2, &sc2);    // 2*pi/256
    float tr2 = 1.0f, ti2 = 0.0f;

#pragma unroll
    for (int h = 0; h < 2; ++h) {
        // write rows m1 = 16h .. 16h+15, interleaved float2
#pragma unroll
        for (int ml = 0; ml < 16; ++ml) {
            const int s = brev5(h * 16 + ml);
            L2[k1 + 32 * (ml * 8 + c2)] =
                make_float2(dre[s] * tr2 - dim2[s] * ti2,
                            dre[s] * ti2 + dim2[s] * tr2);
            float nr = tr2 * sc2 - ti2 * ss2;
            ti2 = tr2 * ss2 + ti2 * sc2;
            tr2 = nr;
        }
        __syncthreads();
        // all threads: DFT-8 for m1 = 16h + c2*2 + q, q = 0,1
#pragma unroll
        for (int q = 0; q < 2; ++q) {
            const int p = h * 2 + q;
            const int ml = c2 * 2 + q;
            float wre[8], wim[8];
#pragma unroll
            for (int c = 0; c < 8; ++c) {
                float2 v = L2[k1 + 32 * (ml * 8 + c)];
                wre[c] = v.x;
                wim[c] = v.y;
            }
            float t0r = wre[0] + wre[4], t0i = wim[0] + wim[4];
            float t1r = wre[0] - wre[4], t1i = wim[0] - wim[4];
            float t2r = wre[2] + wre[6], t2i = wim[2] + wim[6];
            float t3r = wre[2] - wre[6], t3i = wim[2] - wim[6];
            float E0r = t0r + t2r, E0i = t0i + t2i;
            float E2r = t0r - t2r, E2i = t0i - t2i;
            float E1r = t1r - t3i, E1i = t1i + t3r;
            float E3r = t1r + t3i, E3i = t1i - t3r;
            float u0r = wre[1] + wre[5], u0i = wim[1] + wim[5];
            float u1r = wre[1] - wre[5], u1i = wim[1] - wim[5];
            float u2r = wre[3] + wre[7], u2i = wim[3] + wim[7];
            float u3r = wre[3] - wre[7], u3i = wim[3] - wim[7];
            float O0r = u0r + u2r, O0i = u0i + u2i;
            float O2r = u0r - u2r, O2i = u0i - u2i;
            float O1r = u1r - u3i, O1i = u1i + u3r;
            float O3r = u1r + u3i, O3i = u1i - u3r;
            // g = w8^m2 * O
            float g1r = R2 * (O1r - O1i),  g1i = R2 * (O1r + O1i);
            float g2r = -O2i,              g2i = O2r;
            float g3r = -R2 * (O3r + O3i), g3i = R2 * (O3r - O3i);

            sr[p][0] = E0r + O0r;  si[p][0] = E0i + O0i;
            sr[p][1] = E1r + g1r;  si[p][1] = E1i + g1i;
            sr[p][2] = E2r + g2r;  si[p][2] = E2i + g2i;
            sr[p][3] = E3r + g3r;  si[p][3] = E3i + g3i;
            sr[p][4] = E0r - O0r;  si[p][4] = E0i - O0i;
            sr[p][5] = E1r - g1r;  si[p][5] = E1i - g1i;
            sr[p][6] = E2r - g2r;  si[p][6] = E2i - g2i;
            sr[p][7] = E3r - g3r;  si[p][7] = E3i - g3i;
        }
        __syncthreads();
    }

    // ---- Exchange: publish S_z[k], k in [4096,8192), as float2 at k-4096 ----
#pragma unroll
    for (int p = 0; p < 4; ++p) {
        const int m1 = (p >> 1) * 16 + c2 * 2 + (p & 1);
#pragma unroll
        for (int m2 = 4; m2 < 8; ++m2) {
            L2[k1 + 32 * m1 + 1024 * (m2 - 4)] = make_float2(sr[p][m2], si[p][m2]);
        }
    }
    __syncthreads();

    // ---- Combine with conj partner + epilogue; write both rows ----
    const float2 e1v = expk[1];
    const float e1r = e1v.x, e1i = -e1v.y;
    float* ya = y + (size_t)(2 * blk) * NN;
    float* yb = ya + NN;

#pragma unroll
    for (int p = 0; p < 4; ++p) {
        const int m1 = (p >> 1) * 16 + c2 * 2 + (p & 1);
#pragma unroll
        for (int m2 = 0; m2 < 4; ++m2) {
            const int k = k1 + 32 * m1 + 1024 * m2;
            const float2 pv = L2[4095 - k];        // partner k' = 8191-k
            float2 ek = expk[k];
            const float er = ek.x, ei = -ek.y;     // e_k
            const float q2r = er * er - ei * ei;   // e_k^2
            const float q2i = 2.0f * er * ei;
            const float tkr = q2r * e1r - q2i * e1i;   // t_k = e_k^2 * e_1
            const float tki = q2r * e1i + q2i * e1r;
            const float urr = tkr * sr[p][m2] - tki * si[p][m2];  // u = t*Sz[k]
            const float uii = tkr * si[p][m2] + tki * sr[p][m2];
            const float vrr = tkr * pv.x + tki * pv.y;   // v = t*conj(Sz[k'])
            const float vii = tki * pv.x - tkr * pv.y;
            ya[k] = uii + vii;
            yb[k] = vrr - urr;
        }
    }
}

extern "C" void kernel_launch(void* const* d_in, const int* in_sizes, int n_in,
                              void* d_out, int out_size, void* d_ws, size_t ws_size,
                              hipStream_t stream) {
    const float*  x    = (const float*)d_in[0];
    const float2* expk = (const float2*)d_in[1];
    float* out = (float*)d_out;

    idst_fft<<<NN / 2, 256, 0, stream>>>(x, expk, out);
}

// Round 16
// 30.578 us; speedup vs baseline: 4.6625x; 4.6625x over previous
//
#include <hip/hip_runtime.h>

// IDST (DST-III, x2) via a DIRECT N=4096-point complex FFT per 2 rows (no
// zero-padded 8192 FFT, no conj exchange). Derivation (hand-verified N=2,4):
//   z_n = a_n (x^A_n + j x^B_n), a_{N-1} = 1/2
//   C_0 = 2 z_{N-1};  C_p = ê_p (z_{N-1-p} - j z_{p-1}),  ê_p = expk[p]
//   c = IDFT_N(C) (sign +, unnormalized)
//   k even: y^A[k] = Re c_{k/2},        y^B[k] = Im c_{k/2}
//   k odd : y^A[k] = -Re c_{(8191-k)/2}, y^B[k] = -Im c_{(8191-k)/2}
// FFT 4096 = 16 x 16 x 16 (three register DFT-16 stages, two swizzled LDS
// transposes, LDS exactly 32 KB). (256,4): register-safe (R14/R15 lesson).

#define NN 4096

// In-place DFT-16, sign +1, natural order. Radix-4 x radix-4.
__device__ __forceinline__ void dft16(float (&re)[16], float (&im)[16]) {
    const float C1 = 0.92387953f, S1 = 0.38268343f;   // w16^1
    const float C2 = 0.70710678f;                     // w16^2 = (C2,C2)
    float Ar[16], Ai[16];                             // A[s0*4 + f0]
#pragma unroll
    for (int s0 = 0; s0 < 4; ++s0) {
        float ar = re[s0],      ai = im[s0];
        float br = re[s0 + 4],  bi = im[s0 + 4];
        float qr = re[s0 + 8],  qi = im[s0 + 8];
        float dr = re[s0 + 12], di = im[s0 + 12];
        float t0r = ar + qr, t0i = ai + qi;
        float t1r = ar - qr, t1i = ai - qi;
        float t2r = br + dr, t2i = bi + di;
        float t3r = br - dr, t3i = bi - di;
        Ar[s0*4+0] = t0r + t2r;  Ai[s0*4+0] = t0i + t2i;
        Ar[s0*4+1] = t1r - t3i;  Ai[s0*4+1] = t1i + t3r;   // +j t3
        Ar[s0*4+2] = t0r - t2r;  Ai[s0*4+2] = t0i - t2i;
        Ar[s0*4+3] = t1r + t3i;  Ai[s0*4+3] = t1i - t3r;   // -j t3
    }
#pragma unroll
    for (int f0 = 0; f0 < 4; ++f0) {
        float b0r = Ar[f0],      b0i = Ai[f0];
        float a1r = Ar[4 + f0],  a1i = Ai[4 + f0];
        float a2r = Ar[8 + f0],  a2i = Ai[8 + f0];
        float a3r = Ar[12 + f0], a3i = Ai[12 + f0];
        float b1r, b1i, b2r, b2i, b3r, b3i;
        if (f0 == 0) {
            b1r = a1r; b1i = a1i; b2r = a2r; b2i = a2i; b3r = a3r; b3i = a3i;
        } else if (f0 == 1) {
            b1r = a1r*C1 - a1i*S1;  b1i = a1r*S1 + a1i*C1;    // w^1
            b2r = (a2r - a2i)*C2;   b2i = (a2r + a2i)*C2;     // w^2
            b3r = a3r*S1 - a3i*C1;  b3i = a3r*C1 + a3i*S1;    // w^3
        } else if (f0 == 2) {
            b1r = (a1r - a1i)*C2;   b1i = (a1r + a1i)*C2;     // w^2
            b2r = -a2i;             b2i = a2r;                // w^4 = j
            b3r = -(a3r + a3i)*C2;  b3i = (a3r - a3i)*C2;     // w^6
        } else {
            b1r = a1r*S1 - a1i*C1;  b1i = a1r*C1 + a1i*S1;    // w^3
            b2r = -(a2r + a2i)*C2;  b2i = (a2r - a2i)*C2;     // w^6
            b3r = -a3r*C1 + a3i*S1; b3i = -a3r*S1 - a3i*C1;   // w^9
        }
        float t0r = b0r + b2r, t0i = b0i + b2i;
        float t1r = b0r - b2r, t1i = b0i - b2i;
        float t2r = b1r + b3r, t2i = b1i + b3i;
        float t3r = b1r - b3r, t3i = b1i - b3i;
        re[f0]      = t0r + t2r;  im[f0]      = t0i + t2i;
        re[f0 + 4]  = t1r - t3i;  im[f0 + 4]  = t1i + t3r;
        re[f0 + 8]  = t0r - t2r;  im[f0 + 8]  = t0i - t2i;
        re[f0 + 12] = t1r + t3i;  im[f0 + 12] = t1i - t3r;
    }
}

__global__ __launch_bounds__(256, 4) void idst_fft(const float* __restrict__ x,
                                                   const float2* __restrict__ expk,
                                                   float* __restrict__ y) {
    __shared__ float L[8192];            // 32 KB: split re/im planes or float2
    float2* const L2 = (float2*)L;

    const int j = threadIdx.x;
    const int blk = blockIdx.x;
    const float* xa = x + (size_t)(2 * blk) * NN;
    const float* xb = xa + NN;

    // ---- phase 0: stage z ----
#pragma unroll
    for (int i = 0; i < 16; ++i) {
        int n = j + 256 * i;
        float va = xa[n], vb = xb[n];
        if (n == NN - 1) { va *= 0.5f; vb *= 0.5f; }
        L2[n] = make_float2(va, vb);
    }
    __syncthreads();

    // ---- phase 1: build C_p, p = j + 256 s ----
    float cr[16], ci[16];
#pragma unroll
    for (int s = 0; s < 16; ++s) {
        int p = j + 256 * s;
        float2 za = L2[(p == 0) ? 0 : (p - 1)];    // z_{p-1}
        float2 zb = L2[NN - 1 - p];                // z_{N-1-p}
        float2 e = expk[p];
        float er = e.x, ei = -e.y;                 // ê_p
        float wr = zb.x + za.y;                    // zb - j za
        float wi = zb.y - za.x;
        float Cr = er * wr - ei * wi;
        float Ci = er * wi + ei * wr;
        if (p == 0) { Cr = 2.0f * zb.x; Ci = 2.0f * zb.y; }   // C_0 = 2 z_{N-1}
        cr[s] = Cr; ci[s] = Ci;
    }
    __syncthreads();

    // ---- S1: DFT-16 over s -> f; twiddle e^{j2pi j f/4096}; write Y1 ----
    dft16(cr, ci);
    {
        float sn, cs;
        __sincosf((float)j * 1.5339807879e-3f, &sn, &cs);   // 2pi/4096
        float tr = 1.f, ti = 0.f;
#pragma unroll
        for (int f = 0; f < 16; ++f) {
            int a = f * 256 + ((j + 2 * f) & 255);          // rotation swizzle
            L[a]        = cr[f] * tr - ci[f] * ti;
            L[4096 + a] = cr[f] * ti + ci[f] * tr;
            float nr = tr * cs - ti * sn;
            ti = tr * sn + ti * cs;
            tr = nr;
        }
    }
    __syncthreads();

    // ---- S2: (f, jA) = (j&15, j>>4); DFT-16 over jB; twiddle; write Y2 ----
    const int f = j & 15;
    const int jA = j >> 4;
#pragma unroll
    for (int jB = 0; jB < 16; ++jB) {
        int a = f * 256 + ((jA + 16 * jB + 2 * f) & 255);
        cr[jB] = L[a];
        ci[jB] = L[4096 + a];
    }
    dft16(cr, ci);
    __syncthreads();      // Y1 reads complete before overwrite
    {
        float sn, cs;
        __sincosf((float)jA * 2.4543692606e-2f, &sn, &cs);  // 2pi/256
        float tr = 1.f, ti = 0.f;
#pragma unroll
        for (int g0 = 0; g0 < 16; ++g0) {
            int a = ((f + 16 * g0 + 8 * jA) & 255) + 256 * jA;
            L[a]        = cr[g0] * tr - ci[g0] * ti;
            L[4096 + a] = cr[g0] * ti + ci[g0] * tr;
            float nr = tr * cs - ti * sn;
            ti = tr * sn + ti * cs;
            tr = nr;
        }
    }
    __syncthreads();

    // ---- S3: (f, g0) = (j&15, j>>4); DFT-16 over jA' -> g1; write c[q] ----
#pragma unroll
    for (int t = 0; t < 16; ++t) {
        int a = ((f + 16 * (j >> 4) + 8 * t) & 255) + 256 * t;
        cr[t] = L[a];
        ci[t] = L[4096 + a];
    }
    dft16(cr, ci);
    __syncthreads();      // Y2 reads complete
#pragma unroll
    for (int g1 = 0; g1 < 16; ++g1) {
        L2[j + 256 * g1] = make_float2(cr[g1], ci[g1]);   // q = f+16g0+256g1 = j+256g1
    }
    __syncthreads();

    // ---- final: scatter-free output read-off ----
    float* ya = y + (size_t)(2 * blk) * NN;
    float* yb = ya + NN;
#pragma unroll
    for (int i = 0; i < 16; ++i) {
        int k = j + 256 * i;
        int q;
        float sg;
        if (k & 1) { q = (2 * NN - 1 - k) >> 1; sg = -1.0f; }
        else       { q = k >> 1;                sg = 1.0f; }
        float2 v = L2[q];
        ya[k] = sg * v.x;
        yb[k] = sg * v.y;
    }
}

extern "C" void kernel_launch(void* const* d_in, const int* in_sizes, int n_in,
                              void* d_out, int out_size, void* d_ws, size_t ws_size,
                              hipStream_t stream) {
    const float*  x    = (const float*)d_in[0];
    const float2* expk = (const float2*)d_in[1];
    float* out = (float*)d_out;

    idst_fft<<<NN / 2, 256, 0, stream>>>(x, expk, out);
}

// Round 17
// 29.576 us; speedup vs baseline: 4.8204x; 1.0339x over previous
//
#include <hip/hip_runtime.h>

// IDST (DST-III, x2) via DIRECT N=4096-point complex FFT per 2 rows.
//   C_0 = x^A_{N-1} + j x^B_{N-1}   (a_{N-1}=1/2 cancels: C_0 = 2*(1/2)*x)
//   C_p = ê_p (z_{N-1-p} - j z_{p-1}),  ê_p = expk[p]  (no scaling: index
//         N-1 never appears for p>=1)
//   c = IDFT_N(C) (sign +); k even: y = (Re,Im) c_{k/2};
//   k odd: y = -(Re,Im) c_{(2N-1-k)/2}.
// R17 vs R16: (1) phase-0/1 LDS staging replaced by direct (cache-hot)
// global reads of the two z operands; (2) occupancy 4 -> 5 blocks/CU
// ((256,5); state halved since R15's failed attempt, ~80 live regs fits 102).

#define NN 4096

// In-place DFT-16, sign +1, natural order. Radix-4 x radix-4.
__device__ __forceinline__ void dft16(float (&re)[16], float (&im)[16]) {
    const float C1 = 0.92387953f, S1 = 0.38268343f;   // w16^1
    const float C2 = 0.70710678f;                     // w16^2 = (C2,C2)
    float Ar[16], Ai[16];                             // A[s0*4 + f0]
#pragma unroll
    for (int s0 = 0; s0 < 4; ++s0) {
        float ar = re[s0],      ai = im[s0];
        float br = re[s0 + 4],  bi = im[s0 + 4];
        float qr = re[s0 + 8],  qi = im[s0 + 8];
        float dr = re[s0 + 12], di = im[s0 + 12];
        float t0r = ar + qr, t0i = ai + qi;
        float t1r = ar - qr, t1i = ai - qi;
        float t2r = br + dr, t2i = bi + di;
        float t3r = br - dr, t3i = bi - di;
        Ar[s0*4+0] = t0r + t2r;  Ai[s0*4+0] = t0i + t2i;
        Ar[s0*4+1] = t1r - t3i;  Ai[s0*4+1] = t1i + t3r;   // +j t3
        Ar[s0*4+2] = t0r - t2r;  Ai[s0*4+2] = t0i - t2i;
        Ar[s0*4+3] = t1r + t3i;  Ai[s0*4+3] = t1i - t3r;   // -j t3
    }
#pragma unroll
    for (int f0 = 0; f0 < 4; ++f0) {
        float b0r = Ar[f0],      b0i = Ai[f0];
        float a1r = Ar[4 + f0],  a1i = Ai[4 + f0];
        float a2r = Ar[8 + f0],  a2i = Ai[8 + f0];
        float a3r = Ar[12 + f0], a3i = Ai[12 + f0];
        float b1r, b1i, b2r, b2i, b3r, b3i;
        if (f0 == 0) {
            b1r = a1r; b1i = a1i; b2r = a2r; b2i = a2i; b3r = a3r; b3i = a3i;
        } else if (f0 == 1) {
            b1r = a1r*C1 - a1i*S1;  b1i = a1r*S1 + a1i*C1;    // w^1
            b2r = (a2r - a2i)*C2;   b2i = (a2r + a2i)*C2;     // w^2
            b3r = a3r*S1 - a3i*C1;  b3i = a3r*C1 + a3i*S1;    // w^3
        } else if (f0 == 2) {
            b1r = (a1r - a1i)*C2;   b1i = (a1r + a1i)*C2;     // w^2
            b2r = -a2i;             b2i = a2r;                // w^4 = j
            b3r = -(a3r + a3i)*C2;  b3i = (a3r - a3i)*C2;     // w^6
        } else {
            b1r = a1r*S1 - a1i*C1;  b1i = a1r*C1 + a1i*S1;    // w^3
            b2r = -(a2r + a2i)*C2;  b2i = (a2r - a2i)*C2;     // w^6
            b3r = -a3r*C1 + a3i*S1; b3i = -a3r*S1 - a3i*C1;   // w^9
        }
        float t0r = b0r + b2r, t0i = b0i + b2i;
        float t1r = b0r - b2r, t1i = b0i - b2i;
        float t2r = b1r + b3r, t2i = b1i + b3i;
        float t3r = b1r - b3r, t3i = b1i - b3i;
        re[f0]      = t0r + t2r;  im[f0]      = t0i + t2i;
        re[f0 + 4]  = t1r - t3i;  im[f0 + 4]  = t1i + t3r;
        re[f0 + 8]  = t0r - t2r;  im[f0 + 8]  = t0i - t2i;
        re[f0 + 12] = t1r + t3i;  im[f0 + 12] = t1i - t3r;
    }
}

__global__ __launch_bounds__(256, 5) void idst_fft(const float* __restrict__ x,
                                                   const float2* __restrict__ expk,
                                                   float* __restrict__ y) {
    __shared__ float L[8192];            // exactly 32 KB
    float2* const L2 = (float2*)L;

    const int j = threadIdx.x;
    const int blk = blockIdx.x;
    const float* xa = x + (size_t)(2 * blk) * NN;
    const float* xb = xa + NN;

    // ---- build C_p directly from global (p = j + 256 s) ----
    float cr[16], ci[16];
#pragma unroll
    for (int s = 0; s < 16; ++s) {
        const int p = j + 256 * s;
        const int pm1 = (p == 0) ? 0 : (p - 1);
        const float zar = xa[pm1],       zai = xb[pm1];        // z_{p-1}
        const float zbr = xa[NN - 1 - p], zbi = xb[NN - 1 - p]; // z_{N-1-p}
        const float2 e = expk[p];
        const float er = e.x, ei = -e.y;                       // ê_p
        const float wr = zbr + zai;                            // zb - j za
        const float wi = zbi - zar;
        float Cr = er * wr - ei * wi;
        float Ci = er * wi + ei * wr;
        if (p == 0) { Cr = zbr; Ci = zbi; }                    // C_0
        cr[s] = Cr; ci[s] = Ci;
    }

    // ---- S1: DFT-16 over s -> f; twiddle e^{j2pi j f/4096}; write Y1 ----
    dft16(cr, ci);
    {
        float sn, cs;
        __sincosf((float)j * 1.5339807879e-3f, &sn, &cs);   // 2pi/4096
        float tr = 1.f, ti = 0.f;
#pragma unroll
        for (int f = 0; f < 16; ++f) {
            int a = f * 256 + ((j + 2 * f) & 255);          // rotation swizzle
            L[a]        = cr[f] * tr - ci[f] * ti;
            L[4096 + a] = cr[f] * ti + ci[f] * tr;
            float nr = tr * cs - ti * sn;
            ti = tr * sn + ti * cs;
            tr = nr;
        }
    }
    __syncthreads();

    // ---- S2: (f, jA) = (j&15, j>>4); DFT-16 over jB; twiddle; write Y2 ----
    const int f = j & 15;
    const int jA = j >> 4;
#pragma unroll
    for (int jB = 0; jB < 16; ++jB) {
        int a = f * 256 + ((jA + 16 * jB + 2 * f) & 255);
        cr[jB] = L[a];
        ci[jB] = L[4096 + a];
    }
    dft16(cr, ci);
    __syncthreads();      // Y1 reads complete before overwrite
    {
        float sn, cs;
        __sincosf((float)jA * 2.4543692606e-2f, &sn, &cs);  // 2pi/256
        float tr = 1.f, ti = 0.f;
#pragma unroll
        for (int g0 = 0; g0 < 16; ++g0) {
            int a = ((f + 16 * g0 + 8 * jA) & 255) + 256 * jA;
            L[a]        = cr[g0] * tr - ci[g0] * ti;
            L[4096 + a] = cr[g0] * ti + ci[g0] * tr;
            float nr = tr * cs - ti * sn;
            ti = tr * sn + ti * cs;
            tr = nr;
        }
    }
    __syncthreads();

    // ---- S3: (f, g0) = (j&15, j>>4); DFT-16 over jA' -> g1; write c[q] ----
#pragma unroll
    for (int t = 0; t < 16; ++t) {
        int a = ((f + 16 * (j >> 4) + 8 * t) & 255) + 256 * t;
        cr[t] = L[a];
        ci[t] = L[4096 + a];
    }
    dft16(cr, ci);
    __syncthreads();      // Y2 reads complete
#pragma unroll
    for (int g1 = 0; g1 < 16; ++g1) {
        L2[j + 256 * g1] = make_float2(cr[g1], ci[g1]);   // q = j + 256 g1
    }
    __syncthreads();

    // ---- final: output read-off ----
    float* ya = y + (size_t)(2 * blk) * NN;
    float* yb = ya + NN;
#pragma unroll
    for (int i = 0; i < 16; ++i) {
        int k = j + 256 * i;
        int q;
        float sg;
        if (k & 1) { q = (2 * NN - 1 - k) >> 1; sg = -1.0f; }
        else       { q = k >> 1;                sg = 1.0f; }
        float2 v = L2[q];
        ya[k] = sg * v.x;
        yb[k] = sg * v.y;
    }
}

extern "C" void kernel_launch(void* const* d_in, const int* in_sizes, int n_in,
                              void* d_out, int out_size, void* d_ws, size_t ws_size,
                              hipStream_t stream) {
    const float*  x    = (const float*)d_in[0];
    const float2* expk = (const float2*)d_in[1];
    float* out = (float*)d_out;

    idst_fft<<<NN / 2, 256, 0, stream>>>(x, expk, out);
}